// Round 1
// baseline (152.175 us; speedup 1.0000x reference)
//
#include <hip/hip_runtime.h>

#define CCH   256
#define FH    96
#define FW    96
#define HW    (FH*FW)
#define SCALE 0.0625f

#define HROWS 21           // max window rows (span<=19 -> 21); hwin clamped to this
#define PSTR  28           // LDS row stride (floats); cols 24..27 = zeroed pad
#define PLANE (HROWS*PSTR) // 588 floats per wave plane
#define WCH   32           // channels per wave (block = 128ch half-roi, 4 waves)

// R1: latency attack. (a) 4-deep register prefetch (unroll-4 channel loop) so
// the vmcnt wait for channel c's loads has ~4 iterations (~600cy) of lead —
// covers L2/L3 latency that the old 1-deep prefetch exposed every iteration.
// (b) __launch_bounds__(256,6): VGPR cap 84 so weights/taps/staging stay
// resident (old cap 64 forced VGPR=32 -> per-channel rematerialization).
// (c) XCD-pair swizzle: both half-roi blocks of roi k land on the same XCD
// (blockIdx%8 round-robin), so the second block's window reads hit L2.
// Wave-autonomous: each wave owns one LDS plane + 32 channels; no barriers in
// the main loop (within-wave ds ordering is program-order). Every address is
// clamped in-bounds BY CONSTRUCTION.
__global__ __launch_bounds__(256, 6)
void roialign_kernel(const float* __restrict__ feat,
                     const float* __restrict__ rois,
                     float* __restrict__ out)
{
    __shared__ __align__(16) float win[4 * PLANE];
    __shared__ int   s_lo[2][14];
    __shared__ float s_wl[2][14], s_wh[2][14];

    // XCD-pair swizzle: xcd = wgid&7 gets rois [xcd*128, xcd*128+128), each
    // roi's two halves on consecutive per-XCD slots. Bijective on [0,2048).
    const int wgid = blockIdx.x;
    const int k    = (wgid & 7) * 128 + (wgid >> 4);
    const int half = (wgid >> 3) & 1;

    const int tid  = threadIdx.x;
    const int w    = tid >> 6;
    const int ll   = tid & 63;

    // ---------- Phase A: per-roi sample coords ----------
    const float x1 = rois[k*5+1] * SCALE;
    const float y1 = rois[k*5+2] * SCALE;
    const float x2 = rois[k*5+3] * SCALE;
    const float y2 = rois[k*5+4] * SCALE;
    const int   b  = (int)rois[k*5+0];
    const float binw = fmaxf(x2 - x1, 1.0f) * (1.0f/7.0f);
    const float binh = fmaxf(y2 - y1, 1.0f) * (1.0f/7.0f);

    if (tid < 28) {
        const int   axis  = (tid >= 14) ? 1 : 0;
        const int   g     = axis ? tid - 14 : tid;
        const float start = axis ? x1 : y1;
        const float bsz   = axis ? binw : binh;
        const float offs  = (float)(g >> 1) + 0.25f + 0.5f*(float)(g & 1);
        const float coord = start + bsz * offs;
        const bool  valid = (coord >= -1.0f) && (coord <= 96.0f);
        const float cc    = fminf(fmaxf(coord, 0.0f), 95.0f);
        const float lof   = floorf(cc);
        const float frac  = cc - lof;
        const float v     = valid ? 1.0f : 0.0f;
        s_lo[axis][g] = (int)lof;
        s_wl[axis][g] = (1.0f - frac) * v;
        s_wh[axis][g] = frac * v;
    }
    __syncthreads();   // the ONLY barrier

    const int row0 = s_lo[0][0];
    const int col0 = min(s_lo[1][0] & ~3, FW - 24);   // 24-col window always in-image
    int hw_        = min(s_lo[0][13] + 1, FH-1) - row0 + 1;
    const int hwin = min(hw_, HROWS);                 // defensive clamp
    const int nslot = hwin * 6;                       // float4 slots, <=126

    float* const wp = &win[w * PLANE];

    // Zero this wave's plane once: pad cols 24..27 must be finite (weight-0
    // taps can read col clo+1==24 when xlo clamps at 95).
    {
        const float4 z = make_float4(0.f, 0.f, 0.f, 0.f);
        #pragma unroll
        for (int j = 0; j < 3; ++j) {
            const int q = ll + 64*j;
            if (q < PLANE/4) *(float4*)&wp[q*4] = z;
        }
    }

    // ---------- Phase B: tap addresses & pre-scaled weights (channel-invariant) ----------
    const bool active = ll < 49;
    const int  p  = active ? ll : 0;
    const int  oy = p / 7;
    const int  ox = p - oy*7;

    int   aL[4], aH[4];
    float w00[4], w01[4], w10[4], w11[4];
    #pragma unroll
    for (int sy = 0; sy < 2; ++sy) {
        const int   gy  = 2*oy + sy;
        const int   rlo = min(s_lo[0][gy] - row0,                 HROWS-1);
        const int   rhi = min(min(s_lo[0][gy]+1, FH-1) - row0,    HROWS-1);
        const float wyl = s_wl[0][gy], wyh = s_wh[0][gy];
        #pragma unroll
        for (int sx = 0; sx < 2; ++sx) {
            const int   gx  = 2*ox + sx;
            const int   clo = min(s_lo[1][gx] - col0, PSTR-2);    // <=23 provable; clamp anyway
            const float wxl = s_wl[1][gx], wxh = s_wh[1][gx];
            const int   s   = sy*2 + sx;
            aL[s] = rlo*PSTR + clo;
            aH[s] = rhi*PSTR + clo;
            w00[s] = wyl*wxl*0.25f;  w01[s] = wyl*wxh*0.25f;   // 0.25 = sample mean
            w10[s] = wyh*wxl*0.25f;  w11[s] = wyh*wxh*0.25f;
        }
    }

    // ---------- load-slot constants: slots ll and ll+64 of nslot ----------
    const int  sl1 = ll + 64;
    const int  r0  = ll  / 6, q0 = ll  - r0*6;
    const int  r1  = sl1 / 6, q1 = sl1 - r1*6;
    const bool L0  = ll  < nslot;
    const bool L1  = sl1 < nslot;
    // Clamped: legal addresses even for predicated-off lanes.
    const int  goff0 = min(row0 + r0, FH-1)*FW + col0 + q0*4;
    const int  goff1 = min(row0 + r1, FH-1)*FW + col0 + q1*4;
    const int  ld0   = min(r0, HROWS-1)*PSTR + q0*4;
    const int  ld1   = min(r1, HROWS-1)*PSTR + q1*4;

    const int    cb   = half*128 + w*WCH;
    const float* gch  = feat + (size_t)(b*CCH + cb) * HW;
    float*       outp = out  + ((size_t)k*CCH + cb)*49 + p;

    // ---------- 4-deep prefetch prologue: channels 0..3 in flight ----------
    float4 pA0, pA1, pB0, pB1, pC0, pC1, pD0, pD1;
    {
        const float* g0 = gch;
        if (L0) pA0 = *(const float4*)(g0 + goff0);
        if (L1) pA1 = *(const float4*)(g0 + goff1);
        const float* g1 = gch + HW;
        if (L0) pB0 = *(const float4*)(g1 + goff0);
        if (L1) pB1 = *(const float4*)(g1 + goff1);
        const float* g2 = gch + 2*HW;
        if (L0) pC0 = *(const float4*)(g2 + goff0);
        if (L1) pC1 = *(const float4*)(g2 + goff1);
        const float* g3 = gch + 3*HW;
        if (L0) pD0 = *(const float4*)(g3 + goff0);
        if (L1) pD1 = *(const float4*)(g3 + goff1);
    }

    // One channel: drain staged regs to LDS (vmcnt wait has ~4 iters of lead),
    // refill with channel cnext, compute 49 outputs from the plane.
    // Within-wave ds ordering: this channel's ds_reads are issued before the
    // NEXT channel's ds_writes, so the single plane per wave stays race-free.
    auto chan = [&](float4 &s0, float4 &s1, int cnext) {
        if (L0) *(float4*)&wp[ld0] = s0;
        if (L1) *(float4*)&wp[ld1] = s1;
        if (cnext < WCH) {
            const float* gn = gch + (size_t)cnext * HW;
            if (L0) s0 = *(const float4*)(gn + goff0);
            if (L1) s1 = *(const float4*)(gn + goff1);
        }
        if (active) {
            // 4 independent FMA chains (ILP); per-s term order unchanged
            // vs previous version to keep rounding drift minimal.
            float t0 = w00[0]*wp[aL[0]] + w01[0]*wp[aL[0]+1]
                     + w10[0]*wp[aH[0]] + w11[0]*wp[aH[0]+1];
            float t1 = w00[1]*wp[aL[1]] + w01[1]*wp[aL[1]+1]
                     + w10[1]*wp[aH[1]] + w11[1]*wp[aH[1]+1];
            float t2 = w00[2]*wp[aL[2]] + w01[2]*wp[aL[2]+1]
                     + w10[2]*wp[aH[2]] + w11[2]*wp[aH[2]+1];
            float t3 = w00[3]*wp[aL[3]] + w01[3]*wp[aL[3]+1]
                     + w10[3]*wp[aH[3]] + w11[3]*wp[aH[3]+1];
            outp[0] = (t0 + t1) + (t2 + t3);
        }
        outp += 49;
    };

    for (int c = 0; c < WCH; c += 4) {
        chan(pA0, pA1, c + 4);
        chan(pB0, pB1, c + 5);
        chan(pC0, pC1, c + 6);
        chan(pD0, pD1, c + 7);
    }
}

extern "C" void kernel_launch(void* const* d_in, const int* in_sizes, int n_in,
                              void* d_out, int out_size, void* d_ws, size_t ws_size,
                              hipStream_t stream) {
    const float* feat = (const float*)d_in[0];
    const float* rois = (const float*)d_in[1];
    float*       outp = (float*)d_out;
    const int K = in_sizes[1] / 5;   // 1024
    roialign_kernel<<<K*2, 256, 0, stream>>>(feat, rois, outp);
}

// Round 2
// 149.339 us; speedup vs baseline: 1.0190x; 1.0190x over previous
//
#include <hip/hip_runtime.h>

#define CCH   256
#define FH    96
#define FW    96
#define HW    (FH*FW)
#define SCALE 0.0625f

#define RSTR  28            // bin-row stride (floats): rows 16B-aligned; banks 28*oy mod 32
                            // = {0,28,24,20,16,12,8} for oy=0..6 -> all distinct, conflict-free reads
#define PLANE (7*RSTR)      // 196 floats per wave plane (784 B)
#define WCH   32            // channels per wave (block = 128ch half-roi, 4 waves)

// R2: separable y-folding. R0/R1 were LDS-pipe-bound (16 ds_read_b32/output:
// 120Kcy/CU + 34Kcy conflicts ~= the whole 64us). Stage 7 y-interpolated
// bin-rows BR[oy][x] = 0.25*sum_{sy,ty} wy*F[y][x] instead of the raw window:
// compute phase becomes 4 ds_read + 4 FMA per output (was 16+16), staging
// becomes 1 ds_write_b128 per channel (was 2). Validity masks live in wy/wx.
// XCD swizzle of R1 reverted (halves read DIFFERENT channel planes - no
// overlap existed; swizzle only doubled FETCH_SIZE).
// Wave-autonomous: one plane + 32 channels per wave, no barriers in the main
// loop (within-wave DS ops are processed in program order). All addresses
// in-bounds by construction; pad cols 24..27 zeroed once (weight-0 taps).
__global__ __launch_bounds__(256, 6)
void roialign_kernel(const float* __restrict__ feat,
                     const float* __restrict__ rois,
                     float* __restrict__ out)
{
    __shared__ __align__(16) float win[4 * PLANE];
    __shared__ int   s_lo[2][14];
    __shared__ float s_wl[2][14], s_wh[2][14];

    const int k    = blockIdx.x >> 1;
    const int half = blockIdx.x & 1;
    const int tid  = threadIdx.x;
    const int w    = tid >> 6;
    const int ll   = tid & 63;

    // ---------- Phase A: per-roi sample coords ----------
    const float x1 = rois[k*5+1] * SCALE;
    const float y1 = rois[k*5+2] * SCALE;
    const float x2 = rois[k*5+3] * SCALE;
    const float y2 = rois[k*5+4] * SCALE;
    const int   b  = (int)rois[k*5+0];
    const float binw = fmaxf(x2 - x1, 1.0f) * (1.0f/7.0f);
    const float binh = fmaxf(y2 - y1, 1.0f) * (1.0f/7.0f);

    if (tid < 28) {
        const int   axis  = (tid >= 14) ? 1 : 0;
        const int   g     = axis ? tid - 14 : tid;
        const float start = axis ? x1 : y1;
        const float bsz   = axis ? binw : binh;
        const float offs  = (float)(g >> 1) + 0.25f + 0.5f*(float)(g & 1);
        const float coord = start + bsz * offs;
        const bool  valid = (coord >= -1.0f) && (coord <= 96.0f);
        const float cc    = fminf(fmaxf(coord, 0.0f), 95.0f);
        const float lof   = floorf(cc);
        const float frac  = cc - lof;
        // fold the 1/4 sample-mean into the y-axis weights (staging side)
        const float v     = valid ? (axis ? 1.0f : 0.25f) : 0.0f;
        s_lo[axis][g] = (int)lof;
        s_wl[axis][g] = (1.0f - frac) * v;
        s_wh[axis][g] = frac * v;
    }
    __syncthreads();   // the ONLY barrier

    const int col0 = min(s_lo[1][0] & ~3, FW - 24);   // 24-col window always in-image

    float* const wp = &win[w * PLANE];

    // Zero this wave's plane once (PLANE/4 == 49 float4 slots). Pad cols
    // 24..27 of each row are never re-written -> stay 0 for weight-0 taps.
    if (ll < PLANE/4) {
        *(float4*)&wp[ll*4] = make_float4(0.f, 0.f, 0.f, 0.f);
    }

    // ---------- compute-phase constants (channel-invariant) ----------
    const bool active = ll < 49;
    const int  p  = active ? ll : 0;
    const int  oy = p / 7;
    const int  ox = p - oy*7;
    float cw0, cw1, cw2, cw3;
    int   ca0, ca1;
    {
        const int gx0 = 2*ox, gx1 = 2*ox + 1;
        const int c0  = min(s_lo[1][gx0] - col0, 24);   // <=23 provable; pad readable
        const int c1  = min(s_lo[1][gx1] - col0, 24);
        cw0 = s_wl[1][gx0];  cw1 = s_wh[1][gx0];
        cw2 = s_wl[1][gx1];  cw3 = s_wh[1][gx1];
        ca0 = oy*RSTR + c0;
        ca1 = oy*RSTR + c1;
    }

    // ---------- staging constants: slot = (oy, q), 42 slots ----------
    const int  s   = min(ll, 41);          // lanes 42..63 duplicate slot 41 loads (harmless)
    const int  soy = s / 6;
    const int  sq  = s - soy*6;
    const bool st  = ll < 42;              // but only lanes <42 write LDS
    float sw0, sw1, sw2, sw3;
    int   g0, g1, g2, g3;
    {
        const int gy0 = 2*soy, gy1 = 2*soy + 1;
        const int rl0 = s_lo[0][gy0], rh0 = min(rl0 + 1, FH-1);
        const int rl1 = s_lo[0][gy1], rh1 = min(rl1 + 1, FH-1);
        sw0 = s_wl[0][gy0];  sw1 = s_wh[0][gy0];
        sw2 = s_wl[0][gy1];  sw3 = s_wh[0][gy1];
        const int cq = col0 + 4*sq;        // 16B-aligned, in [0, 95-3]
        g0 = rl0*FW + cq;  g1 = rh0*FW + cq;
        g2 = rl1*FW + cq;  g3 = rh1*FW + cq;
    }
    const int ld = soy*RSTR + 4*sq;        // 16B-aligned LDS slot

    const int    cb   = half*128 + w*WCH;
    const float* gch  = feat + (size_t)(b*CCH + cb) * HW;
    float*       outp = out  + ((size_t)k*CCH + cb)*49 + p;

    // ---------- 2-channel register pipeline ----------
    float4 A0, A1, A2, A3, B0, B1, B2, B3;
    {
        const float* ga = gch;
        A0 = *(const float4*)(ga + g0);  A1 = *(const float4*)(ga + g1);
        A2 = *(const float4*)(ga + g2);  A3 = *(const float4*)(ga + g3);
        const float* gb = gch + HW;
        B0 = *(const float4*)(gb + g0);  B1 = *(const float4*)(gb + g1);
        B2 = *(const float4*)(gb + g2);  B3 = *(const float4*)(gb + g3);
    }

    // One channel: y-combine staged rows (16 FMA) -> 1 ds_write_b128; refill
    // the raw regs with channel cnext (2 iters of lead on the vmcnt wait);
    // compute 49 outputs with 4 ds_read + 4 FMA each. Within-wave DS
    // program-order makes write(c) visible to read(c) and keeps read(c)
    // ahead of write(c+1) - single plane per wave stays race-free.
    auto chan = [&](float4& R0, float4& R1, float4& R2, float4& R3, int cnext) {
        float4 v;
        v.x = sw0*R0.x + sw1*R1.x + sw2*R2.x + sw3*R3.x;
        v.y = sw0*R0.y + sw1*R1.y + sw2*R2.y + sw3*R3.y;
        v.z = sw0*R0.z + sw1*R1.z + sw2*R2.z + sw3*R3.z;
        v.w = sw0*R0.w + sw1*R1.w + sw2*R2.w + sw3*R3.w;
        if (st) *(float4*)&wp[ld] = v;

        if (cnext < WCH) {
            const float* gn = gch + (size_t)cnext * HW;
            R0 = *(const float4*)(gn + g0);  R1 = *(const float4*)(gn + g1);
            R2 = *(const float4*)(gn + g2);  R3 = *(const float4*)(gn + g3);
        }

        if (active) {
            outp[0] = cw0*wp[ca0] + cw1*wp[ca0+1]
                    + cw2*wp[ca1] + cw3*wp[ca1+1];
        }
        outp += 49;
    };

    for (int c = 0; c < WCH; c += 2) {
        chan(A0, A1, A2, A3, c + 2);
        chan(B0, B1, B2, B3, c + 3);
    }
}

extern "C" void kernel_launch(void* const* d_in, const int* in_sizes, int n_in,
                              void* d_out, int out_size, void* d_ws, size_t ws_size,
                              hipStream_t stream) {
    const float* feat = (const float*)d_in[0];
    const float* rois = (const float*)d_in[1];
    float*       outp = (float*)d_out;
    const int K = in_sizes[1] / 5;   // 1024
    roialign_kernel<<<K*2, 256, 0, stream>>>(feat, rois, outp);
}